// Round 12
// baseline (3252.496 us; speedup 1.0000x reference)
//
#include <hip/hip_runtime.h>

#define HW_ (512 * 512)
#define B_ 8
#define H_ 512
#define W_ 512
#define K_ 32
#define CH_ 16
#define CHPIX_ (HW_ / CH_)  // 16384 pixels per chunk

typedef float float2v __attribute__((ext_vector_type(2)));

// ---------------- compact phase A: per-chunk valid count ----------------
__global__ void k_count(const float* __restrict__ seg, int* __restrict__ chunkCnt) {
  const int blk = blockIdx.x;  // b*CH_ + c
  const int t = threadIdx.x;
  const float4* __restrict__ s4 = (const float4*)(seg + (size_t)blk * CHPIX_) + (size_t)t * 16;
  int cnt = 0;
#pragma unroll
  for (int j = 0; j < 16; ++j) {
    float4 v = s4[j];
    cnt += (v.x >= 0.9f) + (v.y >= 0.9f) + (v.z >= 0.9f) + (v.w >= 0.9f);
  }
  __shared__ int red[256];
  red[t] = cnt;
  __syncthreads();
  for (int off = 128; off > 0; off >>= 1) {
    if (t < off) red[t] += red[t + off];
    __syncthreads();
  }
  if (t == 0) chunkCnt[blk] = red[0];
}

// ---------------- compact phase B: per-batch chunk base offsets ----------------
__global__ void k_scan(const int* __restrict__ chunkCnt, int* __restrict__ chunkBase,
                       int* __restrict__ nvalid, int cap) {
  const int t = threadIdx.x;  // b*CH_ + c
  if (t < B_ * CH_) {
    const int b = t / CH_, c = t % CH_;
    int base = 0;
    for (int q = 0; q < c; ++q) base += chunkCnt[b * CH_ + q];
    chunkBase[t] = base;
    if (c == CH_ - 1) nvalid[b] = min(base + chunkCnt[t], cap);
  }
}

// ---------------- compact phase C: ordered compaction + gather + lanes memset ----------------
__global__ void k_fill(const float* __restrict__ seg, const float* __restrict__ emb,
                       const int* __restrict__ chunkBase, unsigned char* __restrict__ lanes,
                       int* __restrict__ idxC, float* __restrict__ embC, int cap) {
  const int blk = blockIdx.x;  // b*CH_ + c
  const int b = blk / CH_;
  const int t = threadIdx.x;
  const size_t pixbase = (size_t)blk * CHPIX_ + (size_t)t * 64;
  const float4* __restrict__ s4 = (const float4*)(seg + pixbase);

  int cnt = 0;
#pragma unroll
  for (int j = 0; j < 16; ++j) {
    float4 v = s4[j];
    cnt += (v.x >= 0.9f) + (v.y >= 0.9f) + (v.z >= 0.9f) + (v.w >= 0.9f);
  }
  __shared__ int pre[256];
  pre[t] = cnt;
  __syncthreads();
  for (int off = 1; off < 256; off <<= 1) {
    int mine = pre[t];
    int add = (t >= off) ? pre[t - off] : 0;
    __syncthreads();
    pre[t] = mine + add;
    __syncthreads();
  }
  int w = chunkBase[blk] + pre[t] - cnt;

  uint4 z = {0u, 0u, 0u, 0u};
  uint4* lz = (uint4*)(lanes + pixbase);
  lz[0] = z; lz[1] = z; lz[2] = z; lz[3] = z;

  const float* __restrict__ eb = emb + (size_t)b * 8 * HW_;
  const int pixInB = (int)(pixbase - (size_t)b * HW_);
  for (int j = 0; j < 16; ++j) {
    float4 v = s4[j];
    float sv[4] = {v.x, v.y, v.z, v.w};
#pragma unroll
    for (int q = 0; q < 4; ++q) {
      if (sv[q] >= 0.9f && w < cap) {
        const int p = pixInB + j * 4 + q;
        idxC[(size_t)b * cap + w] = p;
        float* dst = embC + ((size_t)b * cap + w) * 8;
#pragma unroll
        for (int dd = 0; dd < 8; ++dd) dst[dd] = eb[(size_t)dd * HW_ + p];
        ++w;
      }
    }
  }
}

// ---------------- sequential clustering: spec-chain + LDS broadcast + pk ----------------
// 8 blocks x 1 wave, one batch each. Centers on lanes 0-31 (32-63 mirror).
// ON-CHAIN per step (R9 identity, validated): dsq_j = fma(wp, fma(wp, dsqq, m2g),
// dspec) -> key -> 4x DPP min (builtin) -> 2 readlane -> SALU decide -> w.
// OFF-CHAIN (packed float2): C += wp*t; t = s - wp*t; s = e_{j+1} - C;
// dspec = |s|^2; m2g = -2 (t.s).  e arrives via wave-uniform ds_read_b64
// (HW broadcast, natural <2 x float> -> pk codegen; R11 validated).
// 4 rotating e-slots, loaded 3 steps ahead; 32%4==0 keeps slot phase fixed
// across tiles; boundary loads come from the next LDS phase after vmcnt(3).

#define TILE_ 32

__device__ __forceinline__ void stage16(const float* g, float* l) {
  __builtin_amdgcn_global_load_lds(
      (const __attribute__((address_space(1))) void*)g,
      (__attribute__((address_space(3))) void*)l, 16, 0, 0);
}

#define RLU(V, L) ((unsigned)__builtin_amdgcn_readlane((int)(V), (L)))
#define PKF(A, B, C) __builtin_elementwise_fma((A), (B), (C))

#define LOADSLOT4(LS, EBQ, LIDX)          \
  e01_##LS = (EBQ)[(LIDX) * 4 + 0];       \
  e23_##LS = (EBQ)[(LIDX) * 4 + 1];       \
  e45_##LS = (EBQ)[(LIDX) * 4 + 2];       \
  e67_##LS = (EBQ)[(LIDX) * 4 + 3];

// J: step 0..31 (decides pixel J of tile); US = J%4 (slot holding e of px J+1)
#define STEPC(J, US)                                                                 \
  do {                                                                               \
    /* on-chain: corrected dsq for pixel J */                                        \
    float dsq = __builtin_fmaf(wp, __builtin_fmaf(wp, dsqq, m2g), dspec);            \
    unsigned db = __float_as_uint(dsq);                                              \
    unsigned dbm = db > emptyBits ? db : emptyBits; /* empty center -> inf */        \
    unsigned mn = (dbm & 0xFFFFFFE0u) | (unsigned)cl;                                \
    unsigned mr;                                                                     \
    mr = (unsigned)__builtin_amdgcn_update_dpp(0, (int)mn, 0xB1, 0xF, 0xF, true);    \
    mn = mn < mr ? mn : mr;                                                          \
    mr = (unsigned)__builtin_amdgcn_update_dpp(0, (int)mn, 0x4E, 0xF, 0xF, true);    \
    mn = mn < mr ? mn : mr;                                                          \
    mr = (unsigned)__builtin_amdgcn_update_dpp(0, (int)mn, 0x141, 0xF, 0xF, true);   \
    mn = mn < mr ? mn : mr;                                                          \
    mr = (unsigned)__builtin_amdgcn_update_dpp(0, (int)mn, 0x140, 0xF, 0xF, true);   \
    mn = mn < mr ? mn : mr;                                                          \
    unsigned q0 = RLU(mn, 0), q1 = RLU(mn, 16);                                      \
    unsigned mv = q0 < q1 ? q0 : q1; /* uniform -> SALU */                           \
    bool join = mv < 0x41100000u;    /* dsq < 9.0 <=> sqrt(dsq) < 3, exact */        \
    int cid = join ? (int)(mv & 31u) : (nact < 31 ? nact : 31);                      \
    nact += join ? 0 : 1;                                                            \
    bool own = (cl == cid);                                                          \
    float w = own ? (join ? inv : 1.0f) : 0.0f;                                      \
    /* off-chain (packed): apply PREVIOUS pixel's update, correct t, spec next */    \
    float2v wp2 = {wp, wp};                                                          \
    C01 = PKF(wp2, t01, C01); C23 = PKF(wp2, t23, C23);                              \
    C45 = PKF(wp2, t45, C45); C67 = PKF(wp2, t67, C67);                              \
    t01 = PKF(-wp2, t01, s01); t23 = PKF(-wp2, t23, s23);                            \
    t45 = PKF(-wp2, t45, s45); t67 = PKF(-wp2, t67, s67);                            \
    s01 = e01_##US - C01; s23 = e23_##US - C23;                                      \
    s45 = e45_##US - C45; s67 = e67_##US - C67;                                      \
    float2v p = s01 * s01;                                                           \
    p = PKF(s23, s23, p);                                                            \
    p = PKF(s45, s45, p);                                                            \
    p = PKF(s67, s67, p);                                                            \
    dspec = p.x + p.y;                                                               \
    float2v gv = t01 * s01;                                                          \
    gv = PKF(t23, s23, gv);                                                          \
    gv = PKF(t45, s45, gv);                                                          \
    gv = PKF(t67, s67, gv);                                                          \
    m2g = -2.0f * (gv.x + gv.y);                                                     \
    dsqq = dsq;                                                                      \
    wp = w;                                                                          \
    cnt += own ? 1.0f : 0.0f;                                                        \
    inv = __builtin_amdgcn_rcpf(cnt + 1.0f); /* used next step */                    \
    emptyBits = own ? 0u : emptyBits;                                                \
    pk |= (unsigned long long)(unsigned)(cid + 1) << (((J) & 7) * 8);                \
    if (((J) & 7) == 7) {                                                            \
      if (lane == 0) *(unsigned long long*)(cptr + ((J) & ~7)) = pk;                 \
      pk = 0ULL;                                                                     \
    }                                                                                \
  } while (0)

__global__ __launch_bounds__(64, 1) void k_cluster(const float* __restrict__ embC,
                                                   const int* __restrict__ nvalid,
                                                   unsigned char* __restrict__ cidArr,
                                                   int cap) {
  __shared__ float lds[512];  // 2 phases x 256 floats (1KB per phase)
  const int b = blockIdx.x;
  const int lane = threadIdx.x;
  const int cl = lane & 31;
  const int n = nvalid[b];
  if (n <= 0) return;
  const int nTiles = (n + TILE_ - 1) / TILE_;

  const float* src = embC + (size_t)b * cap * 8 + lane * 4;
  unsigned char* cidB = cidArr + (size_t)b * HW_;

  float2v C01 = {0.f, 0.f}, C23 = C01, C45 = C01, C67 = C01;
  float2v t01 = C01, t23 = C01, t45 = C01, t67 = C01;
  float2v s01, s23, s45, s67;
  float2v e01_0, e23_0, e45_0, e67_0;
  float2v e01_1, e23_1, e45_1, e67_1;
  float2v e01_2, e23_2, e45_2, e67_2;
  float2v e01_3, e23_3, e45_3, e67_3;
  float cnt = 0.f, inv = 1.0f, wp = 0.f, m2g = 0.f, dsqq = 0.f, dspec;
  unsigned emptyBits = 0x7F800000u;
  int nact = 0;
  unsigned long long pk = 0ULL;

  // prologue: stage tile 0 into phase 0, wait, init pipeline
  stage16(src, lds);
  asm volatile("s_waitcnt vmcnt(0)" ::: "memory");
  __builtin_amdgcn_sched_barrier(0);
  {
    const float2v* eb0 = (const float2v*)lds;
    // s for pixel 0 against C=0 (t=0 so t-correction yields t = s)
    s01 = eb0[0]; s23 = eb0[1]; s45 = eb0[2]; s67 = eb0[3];
    float2v p = s01 * s01;
    p = PKF(s23, s23, p);
    p = PKF(s45, s45, p);
    p = PKF(s67, s67, p);
    dspec = p.x + p.y;
    // slots 0..2 = e(px1..3); slot 3 filled at step 0
    LOADSLOT4(0, eb0, 1)
    LOADSLOT4(1, eb0, 2)
    LOADSLOT4(2, eb0, 3)
  }

  for (int ti = 0; ti < nTiles; ++ti) {
    const bool more = (ti + 1 < nTiles);
    const float2v* ebq = (const float2v*)((const char*)lds + (ti & 1) * 1024);
    const float2v* ebqN = (const float2v*)((const char*)lds + ((ti + 1) & 1) * 1024);
    unsigned char* cptr = cidB + ti * TILE_;

    if (more)  // stage next tile into the other phase
      stage16(src + (size_t)(ti + 1) * 256, lds + ((ti + 1) & 1) * 256);

    // steps 0..27: load slot (J+3)%4 with e(px J+4) from current phase
    STEPC(0, 0);  LOADSLOT4(3, ebq, 4)
    STEPC(1, 1);  LOADSLOT4(0, ebq, 5)
    STEPC(2, 2);  LOADSLOT4(1, ebq, 6)
    STEPC(3, 3);  LOADSLOT4(2, ebq, 7)
    STEPC(4, 0);  LOADSLOT4(3, ebq, 8)
    STEPC(5, 1);  LOADSLOT4(0, ebq, 9)
    STEPC(6, 2);  LOADSLOT4(1, ebq, 10)
    STEPC(7, 3);  LOADSLOT4(2, ebq, 11)
    STEPC(8, 0);  LOADSLOT4(3, ebq, 12)
    STEPC(9, 1);  LOADSLOT4(0, ebq, 13)
    STEPC(10, 2); LOADSLOT4(1, ebq, 14)
    STEPC(11, 3); LOADSLOT4(2, ebq, 15)
    STEPC(12, 0); LOADSLOT4(3, ebq, 16)
    STEPC(13, 1); LOADSLOT4(0, ebq, 17)
    STEPC(14, 2); LOADSLOT4(1, ebq, 18)
    STEPC(15, 3); LOADSLOT4(2, ebq, 19)
    STEPC(16, 0); LOADSLOT4(3, ebq, 20)
    STEPC(17, 1); LOADSLOT4(0, ebq, 21)
    STEPC(18, 2); LOADSLOT4(1, ebq, 22)
    STEPC(19, 3); LOADSLOT4(2, ebq, 23)
    STEPC(20, 0); LOADSLOT4(3, ebq, 24)
    STEPC(21, 1); LOADSLOT4(0, ebq, 25)
    STEPC(22, 2); LOADSLOT4(1, ebq, 26)
    STEPC(23, 3); LOADSLOT4(2, ebq, 27)
    STEPC(24, 0); LOADSLOT4(3, ebq, 28)
    STEPC(25, 1); LOADSLOT4(0, ebq, 29)
    STEPC(26, 2); LOADSLOT4(1, ebq, 30)
    STEPC(27, 3); LOADSLOT4(2, ebq, 31)

    if (more) {
      // outstanding VMEM (oldest->newest): stage(ti+1), stores@7/15/23 = 4;
      // in-order retirement => vmcnt(3) <=> stage(ti+1) arrived.
      asm volatile("s_waitcnt vmcnt(3)" ::: "memory");
      __builtin_amdgcn_sched_barrier(0);
    }
    // steps 28..31: boundary loads from the NEXT phase (e of next tile px0..3)
    STEPC(28, 0); if (more) { LOADSLOT4(3, ebqN, 0) }
    STEPC(29, 1); if (more) { LOADSLOT4(0, ebqN, 1) }
    STEPC(30, 2); if (more) { LOADSLOT4(1, ebqN, 2) }
    STEPC(31, 3); if (more) { LOADSLOT4(2, ebqN, 3) }
  }
}

// ---------------- scatter cid bytes to the per-pixel lane map ----------------
__global__ void k_scatter(const unsigned char* __restrict__ cidArr,
                          const int* __restrict__ idxC, const int* __restrict__ nvalid,
                          unsigned char* __restrict__ lanes, int cap) {
  const int b = blockIdx.y;
  const int n = nvalid[b];
  for (int j = blockIdx.x * blockDim.x + threadIdx.x; j < n; j += gridDim.x * blockDim.x) {
    lanes[(size_t)b * HW_ + idxC[(size_t)b * cap + j]] = cidArr[(size_t)b * HW_ + j];
  }
}

// ---------------- per-(b,h) segment sums over 33 lane bins ----------------
__global__ void k_rowsum(const unsigned char* __restrict__ lanes,
                         const float* __restrict__ offp, const float* __restrict__ zp,
                         float* __restrict__ cnt, float* __restrict__ sx,
                         float* __restrict__ sz) {
  const int bh = blockIdx.x;
  const int b = bh >> 9, h = bh & 511;
  __shared__ float sc[33], sxx[33], szz[33];
  const int t = threadIdx.x;
  if (t < 33) { sc[t] = 0.f; sxx[t] = 0.f; szz[t] = 0.f; }
  __syncthreads();
  const size_t base = (size_t)bh * W_;
  for (int x = t; x < W_; x += 256) {
    int ln = lanes[base + x];
    float o = offp[base + x];
    float sig = 1.0f / (1.0f + expf(-o));
    float xa = (float)x + sig;
    float zv = zp[base + x];
    atomicAdd(&sc[ln], 1.0f);
    atomicAdd(&sxx[ln], xa);
    atomicAdd(&szz[ln], zv);
  }
  __syncthreads();
  if (t >= 1 && t < 33) {
    size_t o = ((size_t)b * K_ + (t - 1)) * H_ + h;
    cnt[o] = sc[t]; sx[o] = sxx[t]; sz[o] = szz[t];
  }
}

// ---------------- validity + point assembly ----------------
__global__ void k_final(const float* __restrict__ cnt, const float* __restrict__ sx,
                        const float* __restrict__ sz, float* __restrict__ out) {
  const int bk = blockIdx.x;
  const int b = bk >> 5, k = bk & 31;
  const int h = threadIdx.x;
  const size_t o = (size_t)bk * H_ + h;
  float c = cnt[o];
  float sc_ = c, sn = (c > 0.f) ? 1.f : 0.f;
#pragma unroll
  for (int off = 32; off >= 1; off >>= 1) {
    sc_ += __shfl_down(sc_, off);
    sn += __shfl_down(sn, off);
  }
  __shared__ float rs[8], rn[8], tot[2];
  const int wid = h >> 6, lid = h & 63;
  if (lid == 0) { rs[wid] = sc_; rn[wid] = sn; }
  __syncthreads();
  if (h == 0) {
    float a = 0, bb = 0;
#pragma unroll
    for (int q = 0; q < 8; ++q) { a += rs[q]; bb += rn[q]; }
    tot[0] = a; tot[1] = bb;
  }
  __syncthreads();
  float size = tot[0], nrows = tot[1];
  bool valid = (c > 0.f) && (size >= 50.f) && (nrows >= 2.f);
  float mx = sx[o] / fmaxf(c, 1.f);
  float mz = sz[o] / fmaxf(c, 1.f);
  float xw = (512.0f - ((float)h + 0.5f)) * 0.2f;
  float yw = -(mx - 256.0f) * 0.2f;
  out[((size_t)(b * 3 + 0) * K_ + k) * H_ + h] = valid ? xw : 0.f;
  out[((size_t)(b * 3 + 1) * K_ + k) * H_ + h] = valid ? yw : 0.f;
  out[((size_t)(b * 3 + 2) * K_ + k) * H_ + h] = valid ? mz : 0.f;
  out[(size_t)B_ * 3 * K_ * H_ + (size_t)bk * H_ + h] = valid ? 1.f : 0.f;
}

extern "C" void kernel_launch(void* const* d_in, const int* in_sizes, int n_in,
                              void* d_out, int out_size, void* d_ws, size_t ws_size,
                              hipStream_t stream) {
  const float* seg  = (const float*)d_in[0];
  const float* emb  = (const float*)d_in[1];
  const float* offp = (const float*)d_in[2];
  const float* zp   = (const float*)d_in[3];
  float* out = (float*)d_out;
  char* ws = (char*)d_ws;

  const size_t lanesOff = 0;
  const size_t cntOff   = (size_t)B_ * HW_;
  const size_t sxOff    = cntOff + (size_t)B_ * K_ * H_ * 4;
  const size_t szOff    = sxOff  + (size_t)B_ * K_ * H_ * 4;
  const size_t nvOff    = szOff  + (size_t)B_ * K_ * H_ * 4;
  const size_t ccOff    = nvOff + 256;
  const size_t cbOff    = ccOff + 1024;
  const size_t cidOff   = cbOff + 1024;                      // u8 [B][HW_] = 2 MiB
  const size_t idxOff   = cidOff + (size_t)B_ * HW_;
  size_t avail = (ws_size > idxOff + 8192) ? (ws_size - idxOff - 8192) : 0;  // staging slack
  long long capLL = (long long)(avail / ((size_t)B_ * 36));  // 4B idx + 32B emb per entry
  if (capLL > (long long)HW_) capLL = HW_;
  if (capLL < 2) capLL = 2;
  capLL &= ~1LL;  // keep per-batch embC base 64B-aligned
  const int cap = (int)capLL;
  const size_t embOff = idxOff + (size_t)B_ * cap * 4;

  unsigned char* lanes = (unsigned char*)(ws + lanesOff);
  float* cnt = (float*)(ws + cntOff);
  float* sx  = (float*)(ws + sxOff);
  float* sz  = (float*)(ws + szOff);
  int* nvalid = (int*)(ws + nvOff);
  int* chunkCnt  = (int*)(ws + ccOff);
  int* chunkBase = (int*)(ws + cbOff);
  unsigned char* cidArr = (unsigned char*)(ws + cidOff);
  int* idxC   = (int*)(ws + idxOff);
  float* embC = (float*)(ws + embOff);

  k_count<<<B_ * CH_, 256, 0, stream>>>(seg, chunkCnt);
  k_scan<<<1, 128, 0, stream>>>(chunkCnt, chunkBase, nvalid, cap);
  k_fill<<<B_ * CH_, 256, 0, stream>>>(seg, emb, chunkBase, lanes, idxC, embC, cap);
  k_cluster<<<B_, 64, 0, stream>>>(embC, nvalid, cidArr, cap);
  k_scatter<<<dim3(64, B_), 256, 0, stream>>>(cidArr, idxC, nvalid, lanes, cap);
  k_rowsum<<<B_ * H_, 256, 0, stream>>>(lanes, offp, zp, cnt, sx, sz);
  k_final<<<B_ * K_, H_, 0, stream>>>(cnt, sx, sz, out);
}